// Round 1
// baseline (326.443 us; speedup 1.0000x reference)
//
#include <hip/hip_runtime.h>

// SudokuLoss: B=65536 puzzles, G=9, C=10 classes, BS=3.
// 3 threads per puzzle (one per box-row = 3 rows = 27 cells each).
// Row sums + box sums are thread-local; column sums via LDS float atomics.
// Only cells with puzzles==0 (~10%) contribute to ANY output term, so we
// skip logits/targets loads for the other ~90% (exec-masked lanes issue no
// memory transactions).

constexpr int kB = 65536;

__global__ __launch_bounds__(192) void sudoku_main(
    const float* __restrict__ logits,
    const int*   __restrict__ targets,
    const int*   __restrict__ puzzles,
    float*       __restrict__ ws)   // ws[0]=sum diff^2, ws[1]=sum ce, ws[2]=mask count
{
    // colacc layout: [64 puzzles][9 cols][10]: idx j*10+c-1 = class-c sum (c=1..9),
    // idx j*10+9 = per-col mask count.
    __shared__ float colacc[64 * 90];
    __shared__ float red[3][3];

    const int tid = threadIdx.x;
    for (int i = tid; i < 64 * 90; i += 192) colacc[i] = 0.f;
    __syncthreads();

    const int gt = blockIdx.x * 192 + tid;
    const int p  = gt / 3;        // puzzle index
    const int k  = gt % 3;        // box-row (rows 3k..3k+2)
    const int q  = tid / 3;       // puzzle index within block

    const float* lg  = logits  + (size_t)p * 810 + (size_t)k * 270;
    const int*   tgp = targets + (size_t)p * 81  + k * 27;
    const int*   pzp = puzzles + (size_t)p * 81  + k * 27;

    // Pre-load all 27 puzzle entries so the per-cell branches don't form a
    // serialized load->branch dependency chain.
    int pzv[27];
    #pragma unroll
    for (int i = 0; i < 27; ++i) pzv[i] = pzp[i];

    float boxsum[3][9];
    float boxm[3] = {0.f, 0.f, 0.f};
    #pragma unroll
    for (int b = 0; b < 3; ++b)
        #pragma unroll
        for (int c = 0; c < 9; ++c) boxsum[b][c] = 0.f;

    float diff2 = 0.f, ce = 0.f, mcnt = 0.f;
    float* mycol = &colacc[q * 90];

    #pragma unroll
    for (int r = 0; r < 3; ++r) {
        float rowsum[9];
        #pragma unroll
        for (int c = 0; c < 9; ++c) rowsum[c] = 0.f;
        float rowm = 0.f;

        #pragma unroll
        for (int j = 0; j < 9; ++j) {
            const int cell = r * 9 + j;
            if (pzv[cell] == 0) {
                const float* xp = lg + cell * 10;   // always 8B-aligned
                float x[10];
                #pragma unroll
                for (int h = 0; h < 5; ++h) {
                    const float2 v = *(const float2*)(xp + 2 * h);
                    x[2 * h] = v.x; x[2 * h + 1] = v.y;
                }
                float mx = x[0];
                #pragma unroll
                for (int c = 1; c < 10; ++c) mx = fmaxf(mx, x[c]);
                float e[10];
                float S = 0.f;
                #pragma unroll
                for (int c = 0; c < 10; ++c) { e[c] = __expf(x[c] - mx); S += e[c]; }
                const float inv = 1.0f / S;
                const float lse = __logf(S);

                const int t = tgp[cell];
                float xt = x[0];
                #pragma unroll
                for (int c = 1; c < 10; ++c) xt = (t == c) ? x[c] : xt;
                ce   += mx + lse - xt;   // -log_softmax(x)[t]
                mcnt += 1.f;
                rowm += 1.f;
                const int jb = j / 3;    // j unrolled -> compile-time
                boxm[jb] += 1.f;
                atomicAdd(&mycol[j * 10 + 9], 1.f);
                #pragma unroll
                for (int c = 1; c < 10; ++c) {
                    const float w = e[c] * inv;
                    rowsum[c - 1]     += w;
                    boxsum[jb][c - 1] += w;
                    atomicAdd(&mycol[j * 10 + (c - 1)], w);
                }
            }
        }
        // row MSE contribution (classes 1..9 vs rowm/9)
        const float tr = rowm * (1.f / 9.f);
        #pragma unroll
        for (int c = 0; c < 9; ++c) { const float d = rowsum[c] - tr; diff2 += d * d; }
    }
    // box MSE contributions (this thread owns boxes (k, 0..2))
    #pragma unroll
    for (int b = 0; b < 3; ++b) {
        const float tb = boxm[b] * (1.f / 9.f);
        #pragma unroll
        for (int c = 0; c < 9; ++c) { const float d = boxsum[b][c] - tb; diff2 += d * d; }
    }

    __syncthreads();
    // column MSE: thread k of each puzzle handles columns 3k..3k+2
    #pragma unroll
    for (int jj = 0; jj < 3; ++jj) {
        const int j = 3 * k + jj;
        const float tc = mycol[j * 10 + 9] * (1.f / 9.f);
        #pragma unroll
        for (int c = 0; c < 9; ++c) {
            const float d = mycol[j * 10 + c] - tc;
            diff2 += d * d;
        }
    }

    // wave (64-lane) reduction
    #pragma unroll
    for (int off = 32; off > 0; off >>= 1) {
        diff2 += __shfl_down(diff2, off);
        ce    += __shfl_down(ce, off);
        mcnt  += __shfl_down(mcnt, off);
    }
    const int wave = tid >> 6;
    if ((tid & 63) == 0) { red[0][wave] = diff2; red[1][wave] = ce; red[2][wave] = mcnt; }
    __syncthreads();
    if (tid == 0) {
        const float d  = red[0][0] + red[0][1] + red[0][2];
        const float c2 = red[1][0] + red[1][1] + red[1][2];
        const float m  = red[2][0] + red[2][1] + red[2][2];
        atomicAdd(&ws[0], d);
        atomicAdd(&ws[1], c2);
        atomicAdd(&ws[2], m);
    }
}

__global__ void sudoku_final(const float* __restrict__ ws, float* __restrict__ out)
{
    const float diff2   = ws[0];
    const float ce_sum  = ws[1];
    const float msum    = ws[2];
    const float ce_loss = ce_sum / (msum + 1e-8f);
    // each of row/col/box loss = sum(diff^2)/(B*9); constraint = sum/27
    const float constraint = diff2 / ((float)kB * 9.f * 27.f);
    out[0] = ce_loss + 0.1f * constraint;
    out[1] = ce_loss;
    out[2] = constraint;
}

extern "C" void kernel_launch(void* const* d_in, const int* in_sizes, int n_in,
                              void* d_out, int out_size, void* d_ws, size_t ws_size,
                              hipStream_t stream)
{
    const float* logits  = (const float*)d_in[0];
    const int*   targets = (const int*)d_in[1];
    const int*   puzzles = (const int*)d_in[2];
    float* ws  = (float*)d_ws;
    float* out = (float*)d_out;

    hipMemsetAsync(d_ws, 0, 3 * sizeof(float), stream);

    const int blocks = (kB * 3) / 192;   // 1024
    sudoku_main<<<blocks, 192, 0, stream>>>(logits, targets, puzzles, ws);
    sudoku_final<<<1, 1, 0, stream>>>(ws, out);
}